// Round 4
// baseline (589.630 us; speedup 1.0000x reference)
//
#include <hip/hip_runtime.h>
#include <hip/hip_bf16.h>

#define B_ 4096
#define K_ 64
#define N_ 100000
#define E_ 128
#define T_ 3

typedef __bf16 bf16x8 __attribute__((ext_vector_type(8)));
typedef float  f32x4  __attribute__((ext_vector_type(4)));

static __device__ __forceinline__ bf16x8 cvt8r(f32x4 u, f32x4 v) {
    bf16x8 o;
    o[0] = (__bf16)u[0]; o[1] = (__bf16)u[1]; o[2] = (__bf16)u[2]; o[3] = (__bf16)u[3];
    o[4] = (__bf16)v[0]; o[5] = (__bf16)v[1]; o[6] = (__bf16)v[2]; o[7] = (__bf16)v[3];
    return o;
}

// ---------------------------------------------------------------------------
// Kernel 0: transpose + bf16-convert weight matrices.
//   WtF [128][256] <- W_f[256][128];  Wa1t/Wa2t/W1t [128][128]
// ---------------------------------------------------------------------------
__global__ __launch_bounds__(256)
void k_prep(const float* __restrict__ W_f, const float* __restrict__ Wa1,
            const float* __restrict__ Wa2, const float* __restrict__ W1,
            __bf16* __restrict__ WtF, __bf16* __restrict__ Wa1t,
            __bf16* __restrict__ Wa2t, __bf16* __restrict__ W1t) {
    const int n = blockIdx.x;      // output row = original col
    const int k = threadIdx.x;
    if (blockIdx.y == 0) {
        WtF[n * 256 + k] = (__bf16)W_f[k * 128 + n];
    } else if (blockIdx.y == 1) {
        if (k < 128) Wa1t[n * 128 + k] = (__bf16)Wa1[k * 128 + n];
    } else if (blockIdx.y == 2) {
        if (k < 128) Wa2t[n * 128 + k] = (__bf16)Wa2[k * 128 + n];
    } else {
        if (k < 128) W1t[n * 128 + k] = (__bf16)W1[k * 128 + n];
    }
}

// ---------------------------------------------------------------------------
// Kernel 1: nodes_fusion[b] = relu(concat(node_emb[nd], node_prof[nd]) @ W_f + b_f)
// ---------------------------------------------------------------------------
__global__ __launch_bounds__(128)
void k_node_fusion(const int* __restrict__ nodes,
                   const float* __restrict__ node_emb,
                   const float* __restrict__ node_prof,
                   const float* __restrict__ W_f, const float* __restrict__ b_f,
                   __bf16* __restrict__ nodes_fusion) {
    __shared__ float x[256];
    const int b = blockIdx.x;
    const int e = threadIdx.x;          // 0..127
    const int nd = nodes[b];
    x[e]       = node_emb[(size_t)nd * E_ + e];
    x[128 + e] = node_prof[(size_t)nd * E_ + e];
    __syncthreads();
    float acc = b_f[e];
#pragma unroll 8
    for (int i = 0; i < 256; ++i) acc = fmaf(x[i], W_f[i * E_ + e], acc);
    nodes_fusion[(size_t)b * E_ + e] = (__bf16)fmaxf(acc, 0.f);
}

// ---------------------------------------------------------------------------
// Kernel 1b: node_pre[b][c] = ba1[c] + nodes_fusion[b] . Wa1[128+..][c]
// ---------------------------------------------------------------------------
__global__ __launch_bounds__(128)
void k_node_pre(const __bf16* __restrict__ nodes_fusion,
                const float* __restrict__ Wa1, const float* __restrict__ ba1,
                __bf16* __restrict__ node_pre) {
    __shared__ float x[128];
    const int b = blockIdx.x;
    const int c = threadIdx.x;
    x[c] = (float)nodes_fusion[(size_t)b * E_ + c];
    __syncthreads();
    float acc = ba1[c];
#pragma unroll 8
    for (int i = 0; i < 128; ++i) acc = fmaf(x[i], Wa1[(128 + i) * E_ + c], acc);
    node_pre[(size_t)b * E_ + c] = (__bf16)acc;
}

// ---------------------------------------------------------------------------
// Kernel 2 (hot): per (b,t) block, 4 waves of 64.
// Wave w: rows [32*(w>>1),+32) x cols [64*(w&1),+64).
// Gather is a fully-unrolled batched register load (MLP=16/lane), then the
// MFMA K-loop consumes registers — HBM latency stays OUT of the chain.
// ---------------------------------------------------------------------------
__global__ __launch_bounds__(256, 4)
void k_neigh_att(const int* __restrict__ neigh_idx,
                 const float* __restrict__ neigh_emb,
                 const float* __restrict__ neigh_prof,
                 const __bf16* __restrict__ WtF,
                 const __bf16* __restrict__ Wa1t,
                 const __bf16* __restrict__ Wa2t,
                 const float* __restrict__ b_f,
                 const float* __restrict__ ba2,
                 const float* __restrict__ Wa3, const float* __restrict__ ba3,
                 const __bf16* __restrict__ node_pre,
                 __bf16* __restrict__ aggB) {
    __shared__ __bf16 NFl[64 * 136];    // 17408 B
    __shared__ __bf16 H1l[64 * 136];    // 17408 B
    __shared__ float  scp[128];
    __shared__ float  att_s[64];

    const int b    = blockIdx.x;
    const int t    = blockIdx.y;
    const int tid  = threadIdx.x;
    const int wid  = tid >> 6;
    const int lane = tid & 63;
    const int lr   = lane & 15;
    const int lk   = lane >> 4;
    const int mp   = wid >> 1;          // row pair
    const int h    = wid & 1;           // col half

    const int r0 = 32 * mp + lr;
    const int r1 = r0 + 16;

    const float* emb_t   = neigh_emb  + (size_t)t * N_ * E_;
    const float* prof_t  = neigh_prof + (size_t)t * N_ * E_;
    const int*   idx_row = neigh_idx  + ((size_t)t * B_ + b) * K_;

    const int id0 = idx_row[r0];
    const int id1 = idx_row[r1];
    const float* e0p = emb_t  + (size_t)id0 * E_ + lk * 8;
    const float* e1p = emb_t  + (size_t)id1 * E_ + lk * 8;
    const float* p0p = prof_t + (size_t)id0 * E_ + lk * 8;
    const float* p1p = prof_t + (size_t)id1 * E_ + lk * 8;

    // ---- GEMM1: NF = relu(X @ W_f + b_f), K=256, A batched into registers ----
    {
        f32x4 acc[2][4] = {};
        f32x4 sA[8], sB[8];
        // batch-load emb chunks for rows r0,r1 (16 dwordx4 in flight)
#pragma unroll
        for (int ks = 0; ks < 4; ++ks) {
            sA[2 * ks]     = *(const f32x4*)(e0p + ks * 32);
            sA[2 * ks + 1] = *(const f32x4*)(e0p + ks * 32 + 4);
            sB[2 * ks]     = *(const f32x4*)(e1p + ks * 32);
            sB[2 * ks + 1] = *(const f32x4*)(e1p + ks * 32 + 4);
        }
#pragma unroll
        for (int ks = 0; ks < 4; ++ks) {
            const bf16x8 a0 = cvt8r(sA[2 * ks], sA[2 * ks + 1]);
            const bf16x8 a1 = cvt8r(sB[2 * ks], sB[2 * ks + 1]);
            // refill the just-freed slots with the prof chunk for ks+4
            sA[2 * ks]     = *(const f32x4*)(p0p + ks * 32);
            sA[2 * ks + 1] = *(const f32x4*)(p0p + ks * 32 + 4);
            sB[2 * ks]     = *(const f32x4*)(p1p + ks * 32);
            sB[2 * ks + 1] = *(const f32x4*)(p1p + ks * 32 + 4);
            const __bf16* wb = WtF + (size_t)(h * 64 + lr) * 256 + ks * 32 + lk * 8;
#pragma unroll
            for (int n = 0; n < 4; ++n) {
                const bf16x8 w = *(const bf16x8*)(wb + n * 16 * 256);
                acc[0][n] = __builtin_amdgcn_mfma_f32_16x16x32_bf16(a0, w, acc[0][n], 0, 0, 0);
                acc[1][n] = __builtin_amdgcn_mfma_f32_16x16x32_bf16(a1, w, acc[1][n], 0, 0, 0);
            }
        }
#pragma unroll
        for (int ks = 0; ks < 4; ++ks) {
            const bf16x8 a0 = cvt8r(sA[2 * ks], sA[2 * ks + 1]);
            const bf16x8 a1 = cvt8r(sB[2 * ks], sB[2 * ks + 1]);
            const __bf16* wb = WtF + (size_t)(h * 64 + lr) * 256 + (ks + 4) * 32 + lk * 8;
#pragma unroll
            for (int n = 0; n < 4; ++n) {
                const bf16x8 w = *(const bf16x8*)(wb + n * 16 * 256);
                acc[0][n] = __builtin_amdgcn_mfma_f32_16x16x32_bf16(a0, w, acc[0][n], 0, 0, 0);
                acc[1][n] = __builtin_amdgcn_mfma_f32_16x16x32_bf16(a1, w, acc[1][n], 0, 0, 0);
            }
        }
#pragma unroll
        for (int n = 0; n < 4; ++n) {
            const int col = h * 64 + n * 16 + lr;
            const float bb = b_f[col];
#pragma unroll
            for (int j = 0; j < 4; ++j) {
                NFl[(32 * mp + lk * 4 + j) * 136 + col]      = (__bf16)fmaxf(acc[0][n][j] + bb, 0.f);
                NFl[(32 * mp + 16 + lk * 4 + j) * 136 + col] = (__bf16)fmaxf(acc[1][n][j] + bb, 0.f);
            }
        }
    }
    __syncthreads();

    // ---- GEMM2: H1 = relu(NF @ Wa1_top + node_pre), K=128 ----
    {
        f32x4 acc[2][4] = {};
#pragma unroll
        for (int ks = 0; ks < 4; ++ks) {
            const bf16x8 a0 = *(const bf16x8*)&NFl[r0 * 136 + ks * 32 + lk * 8];
            const bf16x8 a1 = *(const bf16x8*)&NFl[r1 * 136 + ks * 32 + lk * 8];
            const __bf16* wb = Wa1t + (size_t)(h * 64 + lr) * 128 + ks * 32 + lk * 8;
#pragma unroll
            for (int n = 0; n < 4; ++n) {
                const bf16x8 w = *(const bf16x8*)(wb + n * 16 * 128);
                acc[0][n] = __builtin_amdgcn_mfma_f32_16x16x32_bf16(a0, w, acc[0][n], 0, 0, 0);
                acc[1][n] = __builtin_amdgcn_mfma_f32_16x16x32_bf16(a1, w, acc[1][n], 0, 0, 0);
            }
        }
#pragma unroll
        for (int n = 0; n < 4; ++n) {
            const int col = h * 64 + n * 16 + lr;
            const float pp = (float)node_pre[(size_t)b * E_ + col];
#pragma unroll
            for (int j = 0; j < 4; ++j) {
                H1l[(32 * mp + lk * 4 + j) * 136 + col]      = (__bf16)fmaxf(acc[0][n][j] + pp, 0.f);
                H1l[(32 * mp + 16 + lk * 4 + j) * 136 + col] = (__bf16)fmaxf(acc[1][n][j] + pp, 0.f);
            }
        }
    }
    __syncthreads();

    // ---- GEMM3 + scores: s = relu(H1 @ Wa2 + ba2) @ Wa3 ----
    {
        f32x4 acc[2][4] = {};
#pragma unroll
        for (int ks = 0; ks < 4; ++ks) {
            const bf16x8 a0 = *(const bf16x8*)&H1l[r0 * 136 + ks * 32 + lk * 8];
            const bf16x8 a1 = *(const bf16x8*)&H1l[r1 * 136 + ks * 32 + lk * 8];
            const __bf16* wb = Wa2t + (size_t)(h * 64 + lr) * 128 + ks * 32 + lk * 8;
#pragma unroll
            for (int n = 0; n < 4; ++n) {
                const bf16x8 w = *(const bf16x8*)(wb + n * 16 * 128);
                acc[0][n] = __builtin_amdgcn_mfma_f32_16x16x32_bf16(a0, w, acc[0][n], 0, 0, 0);
                acc[1][n] = __builtin_amdgcn_mfma_f32_16x16x32_bf16(a1, w, acc[1][n], 0, 0, 0);
            }
        }
        float ba2r[4], wa3r[4];
#pragma unroll
        for (int n = 0; n < 4; ++n) {
            const int col = h * 64 + n * 16 + lr;
            ba2r[n] = ba2[col];
            wa3r[n] = Wa3[col];
        }
#pragma unroll
        for (int mi = 0; mi < 2; ++mi)
#pragma unroll
            for (int j = 0; j < 4; ++j) {
                float v = 0.f;
#pragma unroll
                for (int n = 0; n < 4; ++n)
                    v += fmaxf(acc[mi][n][j] + ba2r[n], 0.f) * wa3r[n];
                v += __shfl_xor(v, 1);
                v += __shfl_xor(v, 2);
                v += __shfl_xor(v, 4);
                v += __shfl_xor(v, 8);
                if (lr == 0)
                    scp[h * 64 + 32 * mp + mi * 16 + lk * 4 + j] = v;
            }
    }
    __syncthreads();

    // ---- softmax over K=64 (wave 0) ----
    if (tid < 64) {
        const float v = scp[tid] + scp[64 + tid] + ba3[0];
        float m = v;
#pragma unroll
        for (int o = 32; o > 0; o >>= 1) m = fmaxf(m, __shfl_xor(m, o));
        const float pe = __expf(v - m);
        float s = pe;
#pragma unroll
        for (int o = 32; o > 0; o >>= 1) s += __shfl_xor(s, o);
        att_s[tid] = pe / s;
    }
    __syncthreads();

    // ---- agg[e] = sum_n att[n] * NF[n][e]  -> bf16 aggB ----
    if (tid < 128) {
        float a = 0.f;
#pragma unroll 8
        for (int n = 0; n < 64; ++n)
            a = fmaf(att_s[n], (float)NFl[n * 136 + tid], a);
        aggB[((size_t)b * T_ + t) * E_ + tid] = (__bf16)a;
    }
}

// ---------------------------------------------------------------------------
// Kernel 2b: type_agg = relu(aggB @ W1 + b1), M=B*T, K=N=128.
// ---------------------------------------------------------------------------
__global__ __launch_bounds__(256)
void k_w1(const __bf16* __restrict__ aggB, const __bf16* __restrict__ W1t,
          const float* __restrict__ b1, __bf16* __restrict__ type_agg) {
    const int tid  = threadIdx.x;
    const int wid  = tid >> 6;
    const int lane = tid & 63;
    const int lr   = lane & 15;
    const int lk   = lane >> 4;
    const int rbase = blockIdx.x * 64 + wid * 16;

    f32x4 acc[8] = {};
#pragma unroll
    for (int ks = 0; ks < 4; ++ks) {
        const bf16x8 a = *(const bf16x8*)&aggB[(size_t)(rbase + lr) * 128 + ks * 32 + lk * 8];
        const __bf16* wb = W1t + (size_t)lr * 128 + ks * 32 + lk * 8;
#pragma unroll
        for (int n = 0; n < 8; ++n) {
            const bf16x8 w = *(const bf16x8*)(wb + n * 16 * 128);
            acc[n] = __builtin_amdgcn_mfma_f32_16x16x32_bf16(a, w, acc[n], 0, 0, 0);
        }
    }
#pragma unroll
    for (int n = 0; n < 8; ++n) {
        const int col = n * 16 + lr;
        const float bb = b1[col];
#pragma unroll
        for (int j = 0; j < 4; ++j) {
            const int row = rbase + lk * 4 + j;
            type_agg[(size_t)row * 128 + col] = (__bf16)fmaxf(acc[n][j] + bb, 0.f);
        }
    }
}

// ---------------------------------------------------------------------------
// Kernel 3: type softmax + final MLP + output head.
// ---------------------------------------------------------------------------
__global__ __launch_bounds__(128)
void k_final(const __bf16* __restrict__ type_agg,
             const __bf16* __restrict__ nodes_fusion,
             const float* __restrict__ Wt,
             const float* __restrict__ W2, const float* __restrict__ b2,
             const float* __restrict__ Wc, const float* __restrict__ bc,
             float* __restrict__ out, float* __restrict__ att_out) {
    __shared__ float ta[384];
    __shared__ float nfu[128];
    __shared__ float fin[128];
    __shared__ float hb[128];
    __shared__ float att[3];
    __shared__ float red[3][128];

    const int b = blockIdx.x;
    const int e = threadIdx.x;   // 0..127

    const float v0 = (float)type_agg[(size_t)b * 384 + e];
    const float v1 = (float)type_agg[(size_t)b * 384 + 128 + e];
    const float v2 = (float)type_agg[(size_t)b * 384 + 256 + e];
    ta[e] = v0; ta[128 + e] = v1; ta[256 + e] = v2;
    nfu[e] = (float)nodes_fusion[(size_t)b * E_ + e];

    float p0, p1, p2;
    {
        const float* w0 = Wt + (size_t)e * 3;
        const float* w1 = Wt + (size_t)(128 + e) * 3;
        const float* w2 = Wt + (size_t)(256 + e) * 3;
        p0 = v0 * w0[0] + v1 * w1[0] + v2 * w2[0];
        p1 = v0 * w0[1] + v1 * w1[1] + v2 * w2[1];
        p2 = v0 * w0[2] + v1 * w1[2] + v2 * w2[2];
    }
    red[0][e] = p0; red[1][e] = p1; red[2][e] = p2;
    __syncthreads();

    if (e < 3) {
        float s = 0.f;
        for (int i = 0; i < 128; ++i) s += red[e][i];
        red[e][0] = s;
    }
    __syncthreads();
    if (e == 0) {
        const float s0 = red[0][0], s1 = red[1][0], s2 = red[2][0];
        const float m  = fmaxf(s0, fmaxf(s1, s2));
        const float e0 = __expf(s0 - m), e1 = __expf(s1 - m), e2 = __expf(s2 - m);
        const float inv = 1.f / (e0 + e1 + e2);
        att[0] = e0 * inv; att[1] = e1 * inv; att[2] = e2 * inv;
    }
    __syncthreads();

    fin[e] = att[0] * ta[e] + att[1] * ta[128 + e] + att[2] * ta[256 + e];
    __syncthreads();

    float acc = b2[e];
#pragma unroll 8
    for (int i = 0; i < 128; ++i) acc = fmaf(fin[i], W2[i * E_ + e], acc);
    hb[e] = fmaxf(acc, 0.f);
    __syncthreads();

    float acc2 = bc[e];
#pragma unroll 8
    for (int i = 0; i < 128; ++i) acc2 = fmaf(nfu[i], Wc[i * E_ + e], acc2);
#pragma unroll 8
    for (int i = 0; i < 128; ++i) acc2 = fmaf(hb[i], Wc[(128 + i) * E_ + e], acc2);
    out[(size_t)b * E_ + e] = fmaxf(acc2, 0.f);

    if (e < 3) att_out[(size_t)b * 3 + e] = att[e];
}

// ---------------------------------------------------------------------------
extern "C" void kernel_launch(void* const* d_in, const int* in_sizes, int n_in,
                              void* d_out, int out_size, void* d_ws, size_t ws_size,
                              hipStream_t stream) {
    const int*   nodes      = (const int*)d_in[0];
    const int*   neigh_idx  = (const int*)d_in[1];
    const float* node_emb   = (const float*)d_in[2];
    const float* node_prof  = (const float*)d_in[3];
    const float* neigh_emb  = (const float*)d_in[4];
    const float* neigh_prof = (const float*)d_in[5];
    const float* W_f = (const float*)d_in[6];  const float* b_f = (const float*)d_in[7];
    const float* Wa1 = (const float*)d_in[8];  const float* ba1 = (const float*)d_in[9];
    const float* Wa2 = (const float*)d_in[10]; const float* ba2 = (const float*)d_in[11];
    const float* Wa3 = (const float*)d_in[12]; const float* ba3 = (const float*)d_in[13];
    const float* W1  = (const float*)d_in[14]; const float* b1  = (const float*)d_in[15];
    const float* W2  = (const float*)d_in[16]; const float* b2  = (const float*)d_in[17];
    const float* Wc  = (const float*)d_in[18]; const float* bc  = (const float*)d_in[19];
    const float* Wt  = (const float*)d_in[20];

    float* out     = (float*)d_out;
    float* att_out = out + (size_t)B_ * E_;

    char* ws = (char*)d_ws;
    __bf16* nodes_fusion = (__bf16*)(ws);                   // 1 MB
    __bf16* node_pre     = (__bf16*)(ws + (1u << 20));      // 1 MB
    __bf16* aggB         = (__bf16*)(ws + (2u << 20));      // 3 MB
    __bf16* type_agg     = (__bf16*)(ws + (5u << 20));      // 3 MB
    __bf16* WtF          = (__bf16*)(ws + (8u << 20));      // 64 KB
    __bf16* Wa1t         = (__bf16*)(ws + (8u << 20) + 65536);
    __bf16* Wa2t         = (__bf16*)(ws + (8u << 20) + 98304);
    __bf16* W1t          = (__bf16*)(ws + (8u << 20) + 131072);

    k_prep<<<dim3(128, 4), 256, 0, stream>>>(W_f, Wa1, Wa2, W1, WtF, Wa1t, Wa2t, W1t);
    k_node_fusion<<<B_, 128, 0, stream>>>(nodes, node_emb, node_prof, W_f, b_f,
                                          nodes_fusion);
    k_node_pre<<<B_, 128, 0, stream>>>(nodes_fusion, Wa1, ba1, node_pre);
    k_neigh_att<<<dim3(B_, T_), 256, 0, stream>>>(neigh_idx, neigh_emb, neigh_prof,
                                                  WtF, Wa1t, Wa2t, b_f, ba2,
                                                  Wa3, ba3, node_pre, aggB);
    k_w1<<<(B_ * T_) / 64, 256, 0, stream>>>(aggB, W1t, b1, type_agg);
    k_final<<<B_, 128, 0, stream>>>(type_agg, nodes_fusion, Wt, W2, b2, Wc, bc,
                                    out, att_out);
}

// Round 5
// 582.995 us; speedup vs baseline: 1.0114x; 1.0114x over previous
//
#include <hip/hip_runtime.h>
#include <hip/hip_bf16.h>

#define B_ 4096
#define K_ 64
#define N_ 100000
#define E_ 128
#define T_ 3

typedef __bf16 bf16x8 __attribute__((ext_vector_type(8)));
typedef float  f32x4  __attribute__((ext_vector_type(4)));

static __device__ __forceinline__ bf16x8 cvt8r(f32x4 u, f32x4 v) {
    bf16x8 o;
    o[0] = (__bf16)u[0]; o[1] = (__bf16)u[1]; o[2] = (__bf16)u[2]; o[3] = (__bf16)u[3];
    o[4] = (__bf16)v[0]; o[5] = (__bf16)v[1]; o[6] = (__bf16)v[2]; o[7] = (__bf16)v[3];
    return o;
}

typedef const __attribute__((address_space(1))) void GAS;
typedef __attribute__((address_space(3))) void LAS;
static __device__ __forceinline__ void gload16(const void* g, void* l) {
    __builtin_amdgcn_global_load_lds((GAS*)g, (LAS*)l, 16, 0, 0);
}

// ---------------------------------------------------------------------------
// Kernel 0: transpose + bf16-convert weight matrices.
//   WtF [128][256] <- W_f[256][128];  Wa1t(top)/Wa2t/W1t [128][128]
// ---------------------------------------------------------------------------
__global__ __launch_bounds__(256)
void k_prep(const float* __restrict__ W_f, const float* __restrict__ Wa1,
            const float* __restrict__ Wa2, const float* __restrict__ W1,
            __bf16* __restrict__ WtF, __bf16* __restrict__ Wa1t,
            __bf16* __restrict__ Wa2t, __bf16* __restrict__ W1t) {
    const int n = blockIdx.x;      // output row = original col
    const int k = threadIdx.x;
    if (blockIdx.y == 0) {
        WtF[n * 256 + k] = (__bf16)W_f[k * 128 + n];
    } else if (blockIdx.y == 1) {
        if (k < 128) Wa1t[n * 128 + k] = (__bf16)Wa1[k * 128 + n];
    } else if (blockIdx.y == 2) {
        if (k < 128) Wa2t[n * 128 + k] = (__bf16)Wa2[k * 128 + n];
    } else {
        if (k < 128) W1t[n * 128 + k] = (__bf16)W1[k * 128 + n];
    }
}

// ---------------------------------------------------------------------------
// Kernel 1: nodes_fusion[b] = relu(concat(node_emb[nd], node_prof[nd]) @ W_f + b_f)
// ---------------------------------------------------------------------------
__global__ __launch_bounds__(128)
void k_node_fusion(const int* __restrict__ nodes,
                   const float* __restrict__ node_emb,
                   const float* __restrict__ node_prof,
                   const float* __restrict__ W_f, const float* __restrict__ b_f,
                   __bf16* __restrict__ nodes_fusion) {
    __shared__ float x[256];
    const int b = blockIdx.x;
    const int e = threadIdx.x;          // 0..127
    const int nd = nodes[b];
    x[e]       = node_emb[(size_t)nd * E_ + e];
    x[128 + e] = node_prof[(size_t)nd * E_ + e];
    __syncthreads();
    float acc = b_f[e];
#pragma unroll 8
    for (int i = 0; i < 256; ++i) acc = fmaf(x[i], W_f[i * E_ + e], acc);
    nodes_fusion[(size_t)b * E_ + e] = (__bf16)fmaxf(acc, 0.f);
}

// ---------------------------------------------------------------------------
// Kernel 1b: node_pre[b][c] = ba1[c] + nodes_fusion[b] . Wa1[128+..][c]  (f32 out)
// ---------------------------------------------------------------------------
__global__ __launch_bounds__(128)
void k_node_pre(const __bf16* __restrict__ nodes_fusion,
                const float* __restrict__ Wa1, const float* __restrict__ ba1,
                float* __restrict__ node_pre) {
    __shared__ float x[128];
    const int b = blockIdx.x;
    const int c = threadIdx.x;
    x[c] = (float)nodes_fusion[(size_t)b * E_ + c];
    __syncthreads();
    float acc = ba1[c];
#pragma unroll 8
    for (int i = 0; i < 128; ++i) acc = fmaf(x[i], Wa1[(128 + i) * E_ + c], acc);
    node_pre[(size_t)b * E_ + c] = acc;
}

// ---------------------------------------------------------------------------
// Kernel NF (dense precompute, per block: 64 rows of type t):
//   NF = relu([emb||prof] @ W_f + b_f)      (LDS only)
//   G  = NF @ Wa1_top                        -> global bf16 (linear layout)
//   M1 = NF @ W1                             -> global bf16
// LDS tiles use granule swizzle p = q ^ (row&15) (16-B granules).
// ---------------------------------------------------------------------------
__global__ __launch_bounds__(256, 3)
void k_nf(const float* __restrict__ neigh_emb,
          const float* __restrict__ neigh_prof,
          const __bf16* __restrict__ WtF, const float* __restrict__ b_f,
          const __bf16* __restrict__ Wa1t, const __bf16* __restrict__ W1t,
          __bf16* __restrict__ G, __bf16* __restrict__ M1) {
    __shared__ __align__(16) __bf16 Xl[64 * 256];    // 32 KB; later G/M1 bounce
    __shared__ __align__(16) __bf16 NFl[64 * 128];   // 16 KB

    const int t    = blockIdx.y;
    const int base = blockIdx.x * 64;
    const int tid  = threadIdx.x;

    // ---- stage X = bf16([emb||prof]) swizzled ----
    {
        const int rr = tid >> 2, qq = tid & 3;
        const int ridx = base + rr;
        const int id = (ridx < N_) ? ridx : (N_ - 1);
        const float* er = neigh_emb  + ((size_t)t * N_ + id) * E_;
        const float* pr = neigh_prof + ((size_t)t * N_ + id) * E_;
#pragma unroll
        for (int j = 0; j < 8; ++j) {
            const int q = qq * 8 + j;                 // global granule 0..31
            const float* s = (q < 16) ? (er + q * 8) : (pr + (q - 16) * 8);
            const f32x4 u = *(const f32x4*)s;
            const f32x4 v = *(const f32x4*)(s + 4);
            *(bf16x8*)&Xl[rr * 256 + ((q ^ (rr & 15)) << 3)] = cvt8r(u, v);
        }
    }
    __syncthreads();

    const int wid = tid >> 6, lane = tid & 63;
    const int lr = lane & 15, lk = lane >> 4;
    const int row = wid * 16 + lr;                    // A-row for both GEMMs

    // ---- GEMM1: NF = relu(X @ W_f + b_f), K=256 ----
    {
        f32x4 acc[8] = {};
#pragma unroll
        for (int ks = 0; ks < 8; ++ks) {
            const int q = ks * 4 + lk;
            const bf16x8 a = *(const bf16x8*)&Xl[row * 256 + ((q ^ (row & 15)) << 3)];
            const __bf16* wb = WtF + (size_t)lr * 256 + ks * 32 + lk * 8;
#pragma unroll
            for (int n = 0; n < 8; ++n) {
                const bf16x8 w = *(const bf16x8*)(wb + (size_t)n * 16 * 256);
                acc[n] = __builtin_amdgcn_mfma_f32_16x16x32_bf16(a, w, acc[n], 0, 0, 0);
            }
        }
#pragma unroll
        for (int n = 0; n < 8; ++n) {
            const int c = n * 16 + lr;
            const float bb = b_f[c];
            const int q = c >> 3, eo = c & 7;
#pragma unroll
            for (int j = 0; j < 4; ++j) {
                const int rN = wid * 16 + lk * 4 + j;
                NFl[rN * 128 + ((q ^ (rN & 15)) << 3) + eo] =
                    (__bf16)fmaxf(acc[n][j] + bb, 0.f);
            }
        }
    }
    __syncthreads();   // NFl ready; Xl dead (all waves past GEMM1)

    // ---- GEMM2a: G = NF @ Wa1t; GEMM2b: M1 = NF @ W1t  (shared A) ----
    {
        f32x4 g2[8] = {}, g3[8] = {};
#pragma unroll
        for (int ks = 0; ks < 4; ++ks) {
            const int q = ks * 4 + lk;
            const bf16x8 a = *(const bf16x8*)&NFl[row * 128 + ((q ^ (row & 15)) << 3)];
            const __bf16* w1b = Wa1t + (size_t)lr * 128 + ks * 32 + lk * 8;
            const __bf16* w2b = W1t  + (size_t)lr * 128 + ks * 32 + lk * 8;
#pragma unroll
            for (int n = 0; n < 8; ++n) {
                g2[n] = __builtin_amdgcn_mfma_f32_16x16x32_bf16(
                    a, *(const bf16x8*)(w1b + (size_t)n * 16 * 128), g2[n], 0, 0, 0);
                g3[n] = __builtin_amdgcn_mfma_f32_16x16x32_bf16(
                    a, *(const bf16x8*)(w2b + (size_t)n * 16 * 128), g3[n], 0, 0, 0);
            }
        }
        __bf16* Gl  = Xl;            // reuse Xl
        __bf16* M1l = Xl + 8192;
#pragma unroll
        for (int n = 0; n < 8; ++n) {
            const int c = n * 16 + lr;
            const int q = c >> 3, eo = c & 7;
#pragma unroll
            for (int j = 0; j < 4; ++j) {
                const int rN = wid * 16 + lk * 4 + j;
                const int sl = rN * 128 + ((q ^ (rN & 15)) << 3) + eo;
                Gl[sl]  = (__bf16)g2[n][j];
                M1l[sl] = (__bf16)g3[n][j];
            }
        }
    }
    __syncthreads();

    // ---- coalesced dump of G/M1 ----
    {
        const __bf16* Gl  = Xl;
        const __bf16* M1l = Xl + 8192;
        const int rr = tid >> 2, qq = tid & 3;
        const int ridx = base + rr;
        if (ridx < N_) {
            __bf16* gout = G  + ((size_t)t * N_ + ridx) * E_;
            __bf16* mout = M1 + ((size_t)t * N_ + ridx) * E_;
#pragma unroll
            for (int g = 0; g < 4; ++g) {
                const int q = qq * 4 + g;
                const int p = q ^ (rr & 15);
                *(bf16x8*)(gout + q * 8) = *(const bf16x8*)&Gl[rr * 128 + (p << 3)];
                *(bf16x8*)(mout + q * 8) = *(const bf16x8*)&M1l[rr * 128 + (p << 3)];
            }
        }
    }
}

// ---------------------------------------------------------------------------
// Kernel ATT (hot): per (b,t) block, 4 waves.
//   gather G,M1 rows via global_load_lds (source pre-swizzled by q^(row&15))
//   H1 = relu(G + node_pre) fused into A-fragment build
//   H2 = relu(H1 @ Wa2 + ba2); s = H2 @ Wa3; att = softmax_K(s)
//   type_agg[b,t] = relu(att^T M1 + b1)
// ---------------------------------------------------------------------------
__global__ __launch_bounds__(256, 4)
void k_att(const int* __restrict__ neigh_idx,
           const __bf16* __restrict__ G, const __bf16* __restrict__ M1,
           const __bf16* __restrict__ Wa2t,
           const float* __restrict__ ba2,
           const float* __restrict__ Wa3, const float* __restrict__ ba3,
           const float* __restrict__ node_pre,
           const float* __restrict__ b1,
           __bf16* __restrict__ type_agg) {
    __shared__ __align__(16) __bf16 Gb[64 * 128];   // 16 KB, swizzled granules
    __shared__ __align__(16) __bf16 Mb[64 * 128];   // 16 KB
    __shared__ float npre[128];
    __shared__ float scp[128];
    __shared__ float att_s[64];
    __shared__ float red2[2][128];

    const int b   = blockIdx.x;
    const int t   = blockIdx.y;
    const int tid = threadIdx.x;
    const int wid = tid >> 6, lane = tid & 63;
    const int lr = lane & 15, lk = lane >> 4;

    if (tid < 128) npre[tid] = node_pre[(size_t)b * E_ + tid];

    const int* idx_row = neigh_idx + ((size_t)t * B_ + b) * K_;

    // ---- gather: wave wid covers rows 16*wid..+15; 4 issues per table ----
    {
#pragma unroll
        for (int i = 0; i < 4; ++i) {
            const int rowblock = wid * 16 + i * 4;
            const int row = rowblock + (lane >> 4);       // 4 rows per issue
            const int q = (lane & 15) ^ (row & 15);       // source pre-swizzle
            const int id = idx_row[row];
            const size_t goff = ((size_t)t * N_ + id) * E_ + q * 8;
            gload16(G + goff,  (char*)Gb + rowblock * 256);
            gload16(M1 + goff, (char*)Mb + rowblock * 256);
        }
    }
    __syncthreads();   // drains vmcnt + lgkmcnt

    // ---- GEMM3: H2 = relu(H1 @ Wa2 + ba2), H1 built on the fly ----
    const int mp = wid >> 1, h = wid & 1;
    const int r0 = 32 * mp + lr, r1 = r0 + 16;            // (r&15)==lr for both
    f32x4 acc[2][4] = {};
#pragma unroll
    for (int ks = 0; ks < 4; ++ks) {
        const int q = ks * 4 + lk;
        const f32x4 n0 = *(const f32x4*)&npre[q * 8];
        const f32x4 n1 = *(const f32x4*)&npre[q * 8 + 4];
        const bf16x8 g0 = *(const bf16x8*)&Gb[r0 * 128 + ((q ^ lr) << 3)];
        const bf16x8 g1 = *(const bf16x8*)&Gb[r1 * 128 + ((q ^ lr) << 3)];
        bf16x8 a0, a1;
#pragma unroll
        for (int j = 0; j < 4; ++j) {
            a0[j]     = (__bf16)fmaxf((float)g0[j]     + n0[j], 0.f);
            a0[j + 4] = (__bf16)fmaxf((float)g0[j + 4] + n1[j], 0.f);
            a1[j]     = (__bf16)fmaxf((float)g1[j]     + n0[j], 0.f);
            a1[j + 4] = (__bf16)fmaxf((float)g1[j + 4] + n1[j], 0.f);
        }
        const __bf16* wb = Wa2t + (size_t)(h * 64 + lr) * 128 + ks * 32 + lk * 8;
#pragma unroll
        for (int n = 0; n < 4; ++n) {
            const bf16x8 w = *(const bf16x8*)(wb + (size_t)n * 16 * 128);
            acc[0][n] = __builtin_amdgcn_mfma_f32_16x16x32_bf16(a0, w, acc[0][n], 0, 0, 0);
            acc[1][n] = __builtin_amdgcn_mfma_f32_16x16x32_bf16(a1, w, acc[1][n], 0, 0, 0);
        }
    }

    // ---- scores: s[row] = sum_c relu(H2+ba2)*Wa3, reduce over lr lanes ----
    {
        float ba2r[4], wa3r[4];
#pragma unroll
        for (int n = 0; n < 4; ++n) {
            const int col = h * 64 + n * 16 + lr;
            ba2r[n] = ba2[col];
            wa3r[n] = Wa3[col];
        }
#pragma unroll
        for (int mi = 0; mi < 2; ++mi)
#pragma unroll
            for (int j = 0; j < 4; ++j) {
                float v = 0.f;
#pragma unroll
                for (int n = 0; n < 4; ++n)
                    v += fmaxf(acc[mi][n][j] + ba2r[n], 0.f) * wa3r[n];
                v += __shfl_xor(v, 1);
                v += __shfl_xor(v, 2);
                v += __shfl_xor(v, 4);
                v += __shfl_xor(v, 8);
                if (lr == 0)
                    scp[h * 64 + 32 * mp + mi * 16 + lk * 4 + j] = v;
            }
    }
    __syncthreads();

    // ---- softmax over K=64 (wave 0) ----
    if (tid < 64) {
        const float v = scp[tid] + scp[64 + tid] + ba3[0];
        float m = v;
#pragma unroll
        for (int o = 32; o > 0; o >>= 1) m = fmaxf(m, __shfl_xor(m, o));
        const float pe = __expf(v - m);
        float s = pe;
#pragma unroll
        for (int o = 32; o > 0; o >>= 1) s += __shfl_xor(s, o);
        att_s[tid] = pe / s;
    }
    __syncthreads();

    // ---- type_agg = relu(att^T M1 + b1) ----
    {
        const int e = tid & 127, half = tid >> 7;
        const int q = e >> 3, eo = e & 7;
        float a = 0.f;
#pragma unroll 8
        for (int n = 0; n < 32; ++n) {
            const int nn = half * 32 + n;
            a = fmaf(att_s[nn], (float)Mb[nn * 128 + ((q ^ (nn & 15)) << 3) + eo], a);
        }
        red2[half][e] = a;
    }
    __syncthreads();
    if (tid < 128) {
        const float s = red2[0][tid] + red2[1][tid];
        type_agg[((size_t)b * T_ + t) * E_ + tid] = (__bf16)fmaxf(s + b1[tid], 0.f);
    }
}

// ---------------------------------------------------------------------------
// Kernel 3: type softmax + final MLP + output head.
// ---------------------------------------------------------------------------
__global__ __launch_bounds__(128)
void k_final(const __bf16* __restrict__ type_agg,
             const __bf16* __restrict__ nodes_fusion,
             const float* __restrict__ Wt,
             const float* __restrict__ W2, const float* __restrict__ b2,
             const float* __restrict__ Wc, const float* __restrict__ bc,
             float* __restrict__ out, float* __restrict__ att_out) {
    __shared__ float ta[384];
    __shared__ float nfu[128];
    __shared__ float fin[128];
    __shared__ float hb[128];
    __shared__ float att[3];
    __shared__ float red[3][128];

    const int b = blockIdx.x;
    const int e = threadIdx.x;   // 0..127

    const float v0 = (float)type_agg[(size_t)b * 384 + e];
    const float v1 = (float)type_agg[(size_t)b * 384 + 128 + e];
    const float v2 = (float)type_agg[(size_t)b * 384 + 256 + e];
    ta[e] = v0; ta[128 + e] = v1; ta[256 + e] = v2;
    nfu[e] = (float)nodes_fusion[(size_t)b * E_ + e];

    float p0, p1, p2;
    {
        const float* w0 = Wt + (size_t)e * 3;
        const float* w1 = Wt + (size_t)(128 + e) * 3;
        const float* w2 = Wt + (size_t)(256 + e) * 3;
        p0 = v0 * w0[0] + v1 * w1[0] + v2 * w2[0];
        p1 = v0 * w0[1] + v1 * w1[1] + v2 * w2[1];
        p2 = v0 * w0[2] + v1 * w1[2] + v2 * w2[2];
    }
    red[0][e] = p0; red[1][e] = p1; red[2][e] = p2;
    __syncthreads();

    if (e < 3) {
        float s = 0.f;
        for (int i = 0; i < 128; ++i) s += red[e][i];
        red[e][0] = s;
    }
    __syncthreads();
    if (e == 0) {
        const float s0 = red[0][0], s1 = red[1][0], s2 = red[2][0];
        const float m  = fmaxf(s0, fmaxf(s1, s2));
        const float e0 = __expf(s0 - m), e1 = __expf(s1 - m), e2 = __expf(s2 - m);
        const float inv = 1.f / (e0 + e1 + e2);
        att[0] = e0 * inv; att[1] = e1 * inv; att[2] = e2 * inv;
    }
    __syncthreads();

    fin[e] = att[0] * ta[e] + att[1] * ta[128 + e] + att[2] * ta[256 + e];
    __syncthreads();

    float acc = b2[e];
#pragma unroll 8
    for (int i = 0; i < 128; ++i) acc = fmaf(fin[i], W2[i * E_ + e], acc);
    hb[e] = fmaxf(acc, 0.f);
    __syncthreads();

    float acc2 = bc[e];
#pragma unroll 8
    for (int i = 0; i < 128; ++i) acc2 = fmaf(nfu[i], Wc[i * E_ + e], acc2);
#pragma unroll 8
    for (int i = 0; i < 128; ++i) acc2 = fmaf(hb[i], Wc[(128 + i) * E_ + e], acc2);
    out[(size_t)b * E_ + e] = fmaxf(acc2, 0.f);

    if (e < 3) att_out[(size_t)b * 3 + e] = att[e];
}

// ---------------------------------------------------------------------------
extern "C" void kernel_launch(void* const* d_in, const int* in_sizes, int n_in,
                              void* d_out, int out_size, void* d_ws, size_t ws_size,
                              hipStream_t stream) {
    const int*   nodes      = (const int*)d_in[0];
    const int*   neigh_idx  = (const int*)d_in[1];
    const float* node_emb   = (const float*)d_in[2];
    const float* node_prof  = (const float*)d_in[3];
    const float* neigh_emb  = (const float*)d_in[4];
    const float* neigh_prof = (const float*)d_in[5];
    const float* W_f = (const float*)d_in[6];  const float* b_f = (const float*)d_in[7];
    const float* Wa1 = (const float*)d_in[8];  const float* ba1 = (const float*)d_in[9];
    const float* Wa2 = (const float*)d_in[10]; const float* ba2 = (const float*)d_in[11];
    const float* Wa3 = (const float*)d_in[12]; const float* ba3 = (const float*)d_in[13];
    const float* W1  = (const float*)d_in[14]; const float* b1  = (const float*)d_in[15];
    const float* W2  = (const float*)d_in[16]; const float* b2  = (const float*)d_in[17];
    const float* Wc  = (const float*)d_in[18]; const float* bc  = (const float*)d_in[19];
    const float* Wt  = (const float*)d_in[20];

    float* out     = (float*)d_out;
    float* att_out = out + (size_t)B_ * E_;

    char* ws = (char*)d_ws;
    __bf16* nodes_fusion = (__bf16*)(ws);                       // 1 MB @ 0
    float*  node_pre     = (float*)(ws + (1u << 20));           // 2 MB @ 1M
    __bf16* type_agg     = (__bf16*)(ws + (3u << 20));          // 3 MB @ 3M
    __bf16* WtF          = (__bf16*)(ws + (6u << 20));          // 64 KB
    __bf16* Wa1t         = (__bf16*)(ws + (6u << 20) + 65536);
    __bf16* Wa2t         = (__bf16*)(ws + (6u << 20) + 98304);
    __bf16* W1t          = (__bf16*)(ws + (6u << 20) + 131072);
    __bf16* Gt           = (__bf16*)(ws + (8u << 20));          // 76.8 MB @ 8M
    __bf16* M1t          = (__bf16*)(ws + (88u << 20));         // 76.8 MB @ 88M

    k_prep<<<dim3(128, 4), 256, 0, stream>>>(W_f, Wa1, Wa2, W1, WtF, Wa1t, Wa2t, W1t);
    k_node_fusion<<<B_, 128, 0, stream>>>(nodes, node_emb, node_prof, W_f, b_f,
                                          nodes_fusion);
    k_node_pre<<<B_, 128, 0, stream>>>(nodes_fusion, Wa1, ba1, node_pre);
    k_nf<<<dim3((N_ + 63) / 64, T_), 256, 0, stream>>>(neigh_emb, neigh_prof,
                                                       WtF, b_f, Wa1t, W1t, Gt, M1t);
    k_att<<<dim3(B_, T_), 256, 0, stream>>>(neigh_idx, Gt, M1t, Wa2t, ba2,
                                            Wa3, ba3, node_pre, b1, type_agg);
    k_final<<<B_, 128, 0, stream>>>(type_agg, nodes_fusion, Wt, W2, b2, Wc, bc,
                                    out, att_out);
}

// Round 6
// 381.260 us; speedup vs baseline: 1.5465x; 1.5291x over previous
//
#include <hip/hip_runtime.h>
#include <hip/hip_bf16.h>

#define B_ 4096
#define K_ 64
#define N_ 100000
#define E_ 128
#define T_ 3

typedef __bf16 bf16x8 __attribute__((ext_vector_type(8)));
typedef float  f32x4  __attribute__((ext_vector_type(4)));

static __device__ __forceinline__ bf16x8 cvt8r(f32x4 u, f32x4 v) {
    bf16x8 o;
    o[0] = (__bf16)u[0]; o[1] = (__bf16)u[1]; o[2] = (__bf16)u[2]; o[3] = (__bf16)u[3];
    o[4] = (__bf16)v[0]; o[5] = (__bf16)v[1]; o[6] = (__bf16)v[2]; o[7] = (__bf16)v[3];
    return o;
}

typedef const __attribute__((address_space(1))) void GAS;
typedef __attribute__((address_space(3))) void LAS;
static __device__ __forceinline__ void gload16(const void* g, void* l) {
    __builtin_amdgcn_global_load_lds((GAS*)g, (LAS*)l, 16, 0, 0);
}

// ---------------------------------------------------------------------------
// Kernel 0: transpose + bf16-convert weight matrices.
//   WtF [128][256] <- W_f[256][128];  Wa1t(top)/Wa2t/W1t [128][128]
// ---------------------------------------------------------------------------
__global__ __launch_bounds__(256)
void k_prep(const float* __restrict__ W_f, const float* __restrict__ Wa1,
            const float* __restrict__ Wa2, const float* __restrict__ W1,
            __bf16* __restrict__ WtF, __bf16* __restrict__ Wa1t,
            __bf16* __restrict__ Wa2t, __bf16* __restrict__ W1t) {
    const int n = blockIdx.x;      // output row = original col
    const int k = threadIdx.x;
    if (blockIdx.y == 0) {
        WtF[n * 256 + k] = (__bf16)W_f[k * 128 + n];
    } else if (blockIdx.y == 1) {
        if (k < 128) Wa1t[n * 128 + k] = (__bf16)Wa1[k * 128 + n];
    } else if (blockIdx.y == 2) {
        if (k < 128) Wa2t[n * 128 + k] = (__bf16)Wa2[k * 128 + n];
    } else {
        if (k < 128) W1t[n * 128 + k] = (__bf16)W1[k * 128 + n];
    }
}

// ---------------------------------------------------------------------------
// Kernel 1: nodes_fusion[b] = relu(concat(node_emb[nd], node_prof[nd]) @ W_f + b_f)
// ---------------------------------------------------------------------------
__global__ __launch_bounds__(128)
void k_node_fusion(const int* __restrict__ nodes,
                   const float* __restrict__ node_emb,
                   const float* __restrict__ node_prof,
                   const float* __restrict__ W_f, const float* __restrict__ b_f,
                   __bf16* __restrict__ nodes_fusion) {
    __shared__ float x[256];
    const int b = blockIdx.x;
    const int e = threadIdx.x;          // 0..127
    const int nd = nodes[b];
    x[e]       = node_emb[(size_t)nd * E_ + e];
    x[128 + e] = node_prof[(size_t)nd * E_ + e];
    __syncthreads();
    float acc = b_f[e];
#pragma unroll 8
    for (int i = 0; i < 256; ++i) acc = fmaf(x[i], W_f[i * E_ + e], acc);
    nodes_fusion[(size_t)b * E_ + e] = (__bf16)fmaxf(acc, 0.f);
}

// ---------------------------------------------------------------------------
// Kernel 1b: node_pre[b][c] = ba1[c] + nodes_fusion[b] . Wa1[128+..][c]  (f32 out)
// ---------------------------------------------------------------------------
__global__ __launch_bounds__(128)
void k_node_pre(const __bf16* __restrict__ nodes_fusion,
                const float* __restrict__ Wa1, const float* __restrict__ ba1,
                float* __restrict__ node_pre) {
    __shared__ float x[128];
    const int b = blockIdx.x;
    const int c = threadIdx.x;
    x[c] = (float)nodes_fusion[(size_t)b * E_ + c];
    __syncthreads();
    float acc = ba1[c];
#pragma unroll 8
    for (int i = 0; i < 128; ++i) acc = fmaf(x[i], Wa1[(128 + i) * E_ + c], acc);
    node_pre[(size_t)b * E_ + c] = acc;
}

// ---------------------------------------------------------------------------
// Kernel NF v2 (dense precompute, per block: 32 rows of type t, 4 waves):
//   X staged as RAW F32 via global_load_lds (fire-and-forget DMA; the whole
//   307 MB HBM stream bypasses VGPRs). bf16 conversion happens at A-fragment
//   build, hidden under MFMA. 16B-granule XOR swizzle p = g ^ (row&15) is
//   applied on the DMA's GLOBAL source and on every LDS read (rule #21).
//   NF = relu(X @ W_f + b_f) (LDS);  G = NF@Wa1_top, M1 = NF@W1 -> global.
//   Wave w owns cols [32w,+32) x all 32 rows.
// ---------------------------------------------------------------------------
__global__ __launch_bounds__(256, 4)
void k_nf(const float* __restrict__ neigh_emb,
          const float* __restrict__ neigh_prof,
          const __bf16* __restrict__ WtF, const float* __restrict__ b_f,
          const __bf16* __restrict__ Wa1t, const __bf16* __restrict__ W1t,
          __bf16* __restrict__ G, __bf16* __restrict__ M1) {
    __shared__ __align__(16) float  Xf[32 * 256];    // 32 KB; later G/M1 bounce
    __shared__ __align__(16) __bf16 NFl[32 * 128];   // 8 KB

    const int t    = blockIdx.y;
    const int base = blockIdx.x * 32;
    const int tid  = threadIdx.x;
    const int wid  = tid >> 6, lane = tid & 63;
    const int lr   = lane & 15, lk = lane >> 4;

    // ---- DMA stage: wave wid -> rows wid*8..+7, one 1KB row per issue ----
    {
        const float* embT  = neigh_emb  + (size_t)t * N_ * E_;
        const float* profT = neigh_prof + (size_t)t * N_ * E_;
#pragma unroll
        for (int i = 0; i < 8; ++i) {
            const int r  = wid * 8 + i;                 // wave-uniform
            const int id = base + r;
            const int g  = lane ^ (r & 15);             // source pre-swizzle
            const float* src = (g < 32)
                ? embT  + (size_t)id * E_ + g * 4
                : profT + (size_t)id * E_ + (g - 32) * 4;
            gload16(src, (char*)Xf + r * 1024);
        }
    }
    __syncthreads();

    // ---- GEMM1: NF = relu(X @ W_f + b_f), K=256 ----
    {
        f32x4 acc1[2][2] = {};                          // [mi][n]
#pragma unroll
        for (int ks = 0; ks < 8; ++ks) {
            const int g0 = ks * 8 + lk * 2;             // f32 16B-granule
            const f32x4 u0 = *(const f32x4*)&Xf[lr * 256 + ((g0 ^ lr) << 2)];
            const f32x4 v0 = *(const f32x4*)&Xf[lr * 256 + (((g0 + 1) ^ lr) << 2)];
            const f32x4 u1 = *(const f32x4*)&Xf[(16 + lr) * 256 + ((g0 ^ lr) << 2)];
            const f32x4 v1 = *(const f32x4*)&Xf[(16 + lr) * 256 + (((g0 + 1) ^ lr) << 2)];
            const bf16x8 a0 = cvt8r(u0, v0);
            const bf16x8 a1 = cvt8r(u1, v1);
#pragma unroll
            for (int n = 0; n < 2; ++n) {
                const int c = wid * 32 + n * 16 + lr;
                const bf16x8 w = *(const bf16x8*)&WtF[(size_t)c * 256 + ks * 32 + lk * 8];
                acc1[0][n] = __builtin_amdgcn_mfma_f32_16x16x32_bf16(a0, w, acc1[0][n], 0, 0, 0);
                acc1[1][n] = __builtin_amdgcn_mfma_f32_16x16x32_bf16(a1, w, acc1[1][n], 0, 0, 0);
            }
        }
#pragma unroll
        for (int n = 0; n < 2; ++n) {
            const int c = wid * 32 + n * 16 + lr;
            const float bb = b_f[c];
            const int q = c >> 3, eo = c & 7;
#pragma unroll
            for (int mi = 0; mi < 2; ++mi)
#pragma unroll
                for (int j = 0; j < 4; ++j) {
                    const int rN = mi * 16 + lk * 4 + j;
                    NFl[rN * 128 + ((q ^ (rN & 15)) << 3) + eo] =
                        (__bf16)fmaxf(acc1[mi][n][j] + bb, 0.f);
                }
        }
    }
    __syncthreads();   // NF ready; all waves past GEMM1 -> Xf dead

    // ---- GEMM2a/b: G = NF @ Wa1t, M1 = NF @ W1t (shared A) ----
    {
        f32x4 g2[2][2] = {}, g3[2][2] = {};
#pragma unroll
        for (int ks = 0; ks < 4; ++ks) {
            const int q = ks * 4 + lk;                  // bf16 16B-granule
            const bf16x8 a0 = *(const bf16x8*)&NFl[lr * 128 + ((q ^ lr) << 3)];
            const bf16x8 a1 = *(const bf16x8*)&NFl[(16 + lr) * 128 + ((q ^ lr) << 3)];
#pragma unroll
            for (int n = 0; n < 2; ++n) {
                const int c = wid * 32 + n * 16 + lr;
                const bf16x8 wv1 = *(const bf16x8*)&Wa1t[(size_t)c * 128 + ks * 32 + lk * 8];
                const bf16x8 wv2 = *(const bf16x8*)&W1t[(size_t)c * 128 + ks * 32 + lk * 8];
                g2[0][n] = __builtin_amdgcn_mfma_f32_16x16x32_bf16(a0, wv1, g2[0][n], 0, 0, 0);
                g2[1][n] = __builtin_amdgcn_mfma_f32_16x16x32_bf16(a1, wv1, g2[1][n], 0, 0, 0);
                g3[0][n] = __builtin_amdgcn_mfma_f32_16x16x32_bf16(a0, wv2, g3[0][n], 0, 0, 0);
                g3[1][n] = __builtin_amdgcn_mfma_f32_16x16x32_bf16(a1, wv2, g3[1][n], 0, 0, 0);
            }
        }
        __bf16* Gl  = (__bf16*)Xf;                      // bounce in dead Xf
        __bf16* M1l = (__bf16*)Xf + 4096;
#pragma unroll
        for (int n = 0; n < 2; ++n) {
            const int c = wid * 32 + n * 16 + lr;
            const int q = c >> 3, eo = c & 7;
#pragma unroll
            for (int mi = 0; mi < 2; ++mi)
#pragma unroll
                for (int j = 0; j < 4; ++j) {
                    const int rN = mi * 16 + lk * 4 + j;
                    const int sl = rN * 128 + ((q ^ (rN & 15)) << 3) + eo;
                    Gl[sl]  = (__bf16)g2[mi][n][j];
                    M1l[sl] = (__bf16)g3[mi][n][j];
                }
        }
    }
    __syncthreads();

    // ---- coalesced dump of G/M1 ----
    {
        const __bf16* Gl  = (const __bf16*)Xf;
        const __bf16* M1l = (const __bf16*)Xf + 4096;
        const int rr = tid >> 3, qq = tid & 7;
        const int ridx = base + rr;
        __bf16* gout = G  + ((size_t)t * N_ + ridx) * E_;
        __bf16* mout = M1 + ((size_t)t * N_ + ridx) * E_;
#pragma unroll
        for (int g = 0; g < 2; ++g) {
            const int q = qq * 2 + g;
            const int p = q ^ (rr & 15);
            *(bf16x8*)(gout + q * 8) = *(const bf16x8*)&Gl[rr * 128 + (p << 3)];
            *(bf16x8*)(mout + q * 8) = *(const bf16x8*)&M1l[rr * 128 + (p << 3)];
        }
    }
}

// ---------------------------------------------------------------------------
// Kernel ATT (hot): per (b,t) block, 4 waves.
//   gather G,M1 rows via global_load_lds (source pre-swizzled by q^(row&15))
//   H1 = relu(G + node_pre) fused into A-fragment build
//   H2 = relu(H1 @ Wa2 + ba2); s = H2 @ Wa3; att = softmax_K(s)
//   type_agg[b,t] = relu(att^T M1 + b1)
// ---------------------------------------------------------------------------
__global__ __launch_bounds__(256, 4)
void k_att(const int* __restrict__ neigh_idx,
           const __bf16* __restrict__ G, const __bf16* __restrict__ M1,
           const __bf16* __restrict__ Wa2t,
           const float* __restrict__ ba2,
           const float* __restrict__ Wa3, const float* __restrict__ ba3,
           const float* __restrict__ node_pre,
           const float* __restrict__ b1,
           __bf16* __restrict__ type_agg) {
    __shared__ __align__(16) __bf16 Gb[64 * 128];   // 16 KB, swizzled granules
    __shared__ __align__(16) __bf16 Mb[64 * 128];   // 16 KB
    __shared__ float npre[128];
    __shared__ float scp[128];
    __shared__ float att_s[64];
    __shared__ float red2[2][128];

    const int b   = blockIdx.x;
    const int t   = blockIdx.y;
    const int tid = threadIdx.x;
    const int wid = tid >> 6, lane = tid & 63;
    const int lr = lane & 15, lk = lane >> 4;

    if (tid < 128) npre[tid] = node_pre[(size_t)b * E_ + tid];

    const int* idx_row = neigh_idx + ((size_t)t * B_ + b) * K_;

    // ---- gather: wave wid covers rows 16*wid..+15; 4 issues per table ----
    {
#pragma unroll
        for (int i = 0; i < 4; ++i) {
            const int rowblock = wid * 16 + i * 4;
            const int row = rowblock + (lane >> 4);       // 4 rows per issue
            const int q = (lane & 15) ^ (row & 15);       // source pre-swizzle
            const int id = idx_row[row];
            const size_t goff = ((size_t)t * N_ + id) * E_ + q * 8;
            gload16(G + goff,  (char*)Gb + rowblock * 256);
            gload16(M1 + goff, (char*)Mb + rowblock * 256);
        }
    }
    __syncthreads();   // drains vmcnt + lgkmcnt

    // ---- GEMM3: H2 = relu(H1 @ Wa2 + ba2), H1 built on the fly ----
    const int mp = wid >> 1, h = wid & 1;
    const int r0 = 32 * mp + lr, r1 = r0 + 16;            // (r&15)==lr for both
    f32x4 acc[2][4] = {};
#pragma unroll
    for (int ks = 0; ks < 4; ++ks) {
        const int q = ks * 4 + lk;
        const f32x4 n0 = *(const f32x4*)&npre[q * 8];
        const f32x4 n1 = *(const f32x4*)&npre[q * 8 + 4];
        const bf16x8 g0 = *(const bf16x8*)&Gb[r0 * 128 + ((q ^ lr) << 3)];
        const bf16x8 g1 = *(const bf16x8*)&Gb[r1 * 128 + ((q ^ lr) << 3)];
        bf16x8 a0, a1;
#pragma unroll
        for (int j = 0; j < 4; ++j) {
            a0[j]     = (__bf16)fmaxf((float)g0[j]     + n0[j], 0.f);
            a0[j + 4] = (__bf16)fmaxf((float)g0[j + 4] + n1[j], 0.f);
            a1[j]     = (__bf16)fmaxf((float)g1[j]     + n0[j], 0.f);
            a1[j + 4] = (__bf16)fmaxf((float)g1[j + 4] + n1[j], 0.f);
        }
        const __bf16* wb = Wa2t + (size_t)(h * 64 + lr) * 128 + ks * 32 + lk * 8;
#pragma unroll
        for (int n = 0; n < 4; ++n) {
            const bf16x8 w = *(const bf16x8*)(wb + (size_t)n * 16 * 128);
            acc[0][n] = __builtin_amdgcn_mfma_f32_16x16x32_bf16(a0, w, acc[0][n], 0, 0, 0);
            acc[1][n] = __builtin_amdgcn_mfma_f32_16x16x32_bf16(a1, w, acc[1][n], 0, 0, 0);
        }
    }

    // ---- scores: s[row] = sum_c relu(H2+ba2)*Wa3, reduce over lr lanes ----
    {
        float ba2r[4], wa3r[4];
#pragma unroll
        for (int n = 0; n < 4; ++n) {
            const int col = h * 64 + n * 16 + lr;
            ba2r[n] = ba2[col];
            wa3r[n] = Wa3[col];
        }
#pragma unroll
        for (int mi = 0; mi < 2; ++mi)
#pragma unroll
            for (int j = 0; j < 4; ++j) {
                float v = 0.f;
#pragma unroll
                for (int n = 0; n < 4; ++n)
                    v += fmaxf(acc[mi][n][j] + ba2r[n], 0.f) * wa3r[n];
                v += __shfl_xor(v, 1);
                v += __shfl_xor(v, 2);
                v += __shfl_xor(v, 4);
                v += __shfl_xor(v, 8);
                if (lr == 0)
                    scp[h * 64 + 32 * mp + mi * 16 + lk * 4 + j] = v;
            }
    }
    __syncthreads();

    // ---- softmax over K=64 (wave 0) ----
    if (tid < 64) {
        const float v = scp[tid] + scp[64 + tid] + ba3[0];
        float m = v;
#pragma unroll
        for (int o = 32; o > 0; o >>= 1) m = fmaxf(m, __shfl_xor(m, o));
        const float pe = __expf(v - m);
        float s = pe;
#pragma unroll
        for (int o = 32; o > 0; o >>= 1) s += __shfl_xor(s, o);
        att_s[tid] = pe / s;
    }
    __syncthreads();

    // ---- type_agg = relu(att^T M1 + b1) ----
    {
        const int e = tid & 127, half = tid >> 7;
        const int q = e >> 3, eo = e & 7;
        float a = 0.f;
#pragma unroll 8
        for (int n = 0; n < 32; ++n) {
            const int nn = half * 32 + n;
            a = fmaf(att_s[nn], (float)Mb[nn * 128 + ((q ^ (nn & 15)) << 3) + eo], a);
        }
        red2[half][e] = a;
    }
    __syncthreads();
    if (tid < 128) {
        const float s = red2[0][tid] + red2[1][tid];
        type_agg[((size_t)b * T_ + t) * E_ + tid] = (__bf16)fmaxf(s + b1[tid], 0.f);
    }
}

// ---------------------------------------------------------------------------
// Kernel 3: type softmax + final MLP + output head.
// ---------------------------------------------------------------------------
__global__ __launch_bounds__(128)
void k_final(const __bf16* __restrict__ type_agg,
             const __bf16* __restrict__ nodes_fusion,
             const float* __restrict__ Wt,
             const float* __restrict__ W2, const float* __restrict__ b2,
             const float* __restrict__ Wc, const float* __restrict__ bc,
             float* __restrict__ out, float* __restrict__ att_out) {
    __shared__ float ta[384];
    __shared__ float nfu[128];
    __shared__ float fin[128];
    __shared__ float hb[128];
    __shared__ float att[3];
    __shared__ float red[3][128];

    const int b = blockIdx.x;
    const int e = threadIdx.x;   // 0..127

    const float v0 = (float)type_agg[(size_t)b * 384 + e];
    const float v1 = (float)type_agg[(size_t)b * 384 + 128 + e];
    const float v2 = (float)type_agg[(size_t)b * 384 + 256 + e];
    ta[e] = v0; ta[128 + e] = v1; ta[256 + e] = v2;
    nfu[e] = (float)nodes_fusion[(size_t)b * E_ + e];

    float p0, p1, p2;
    {
        const float* w0 = Wt + (size_t)e * 3;
        const float* w1 = Wt + (size_t)(128 + e) * 3;
        const float* w2 = Wt + (size_t)(256 + e) * 3;
        p0 = v0 * w0[0] + v1 * w1[0] + v2 * w2[0];
        p1 = v0 * w0[1] + v1 * w1[1] + v2 * w2[1];
        p2 = v0 * w0[2] + v1 * w1[2] + v2 * w2[2];
    }
    red[0][e] = p0; red[1][e] = p1; red[2][e] = p2;
    __syncthreads();

    if (e < 3) {
        float s = 0.f;
        for (int i = 0; i < 128; ++i) s += red[e][i];
        red[e][0] = s;
    }
    __syncthreads();
    if (e == 0) {
        const float s0 = red[0][0], s1 = red[1][0], s2 = red[2][0];
        const float m  = fmaxf(s0, fmaxf(s1, s2));
        const float e0 = __expf(s0 - m), e1 = __expf(s1 - m), e2 = __expf(s2 - m);
        const float inv = 1.f / (e0 + e1 + e2);
        att[0] = e0 * inv; att[1] = e1 * inv; att[2] = e2 * inv;
    }
    __syncthreads();

    fin[e] = att[0] * ta[e] + att[1] * ta[128 + e] + att[2] * ta[256 + e];
    __syncthreads();

    float acc = b2[e];
#pragma unroll 8
    for (int i = 0; i < 128; ++i) acc = fmaf(fin[i], W2[i * E_ + e], acc);
    hb[e] = fmaxf(acc, 0.f);
    __syncthreads();

    float acc2 = bc[e];
#pragma unroll 8
    for (int i = 0; i < 128; ++i) acc2 = fmaf(nfu[i], Wc[i * E_ + e], acc2);
#pragma unroll 8
    for (int i = 0; i < 128; ++i) acc2 = fmaf(hb[i], Wc[(128 + i) * E_ + e], acc2);
    out[(size_t)b * E_ + e] = fmaxf(acc2, 0.f);

    if (e < 3) att_out[(size_t)b * 3 + e] = att[e];
}

// ---------------------------------------------------------------------------
extern "C" void kernel_launch(void* const* d_in, const int* in_sizes, int n_in,
                              void* d_out, int out_size, void* d_ws, size_t ws_size,
                              hipStream_t stream) {
    const int*   nodes      = (const int*)d_in[0];
    const int*   neigh_idx  = (const int*)d_in[1];
    const float* node_emb   = (const float*)d_in[2];
    const float* node_prof  = (const float*)d_in[3];
    const float* neigh_emb  = (const float*)d_in[4];
    const float* neigh_prof = (const float*)d_in[5];
    const float* W_f = (const float*)d_in[6];  const float* b_f = (const float*)d_in[7];
    const float* Wa1 = (const float*)d_in[8];  const float* ba1 = (const float*)d_in[9];
    const float* Wa2 = (const float*)d_in[10]; const float* ba2 = (const float*)d_in[11];
    const float* Wa3 = (const float*)d_in[12]; const float* ba3 = (const float*)d_in[13];
    const float* W1  = (const float*)d_in[14]; const float* b1  = (const float*)d_in[15];
    const float* W2  = (const float*)d_in[16]; const float* b2  = (const float*)d_in[17];
    const float* Wc  = (const float*)d_in[18]; const float* bc  = (const float*)d_in[19];
    const float* Wt  = (const float*)d_in[20];

    float* out     = (float*)d_out;
    float* att_out = out + (size_t)B_ * E_;

    char* ws = (char*)d_ws;
    __bf16* nodes_fusion = (__bf16*)(ws);                       // 1 MB @ 0
    float*  node_pre     = (float*)(ws + (1u << 20));           // 2 MB @ 1M
    __bf16* type_agg     = (__bf16*)(ws + (3u << 20));          // 3 MB @ 3M
    __bf16* WtF          = (__bf16*)(ws + (6u << 20));          // 64 KB
    __bf16* Wa1t         = (__bf16*)(ws + (6u << 20) + 65536);
    __bf16* Wa2t         = (__bf16*)(ws + (6u << 20) + 98304);
    __bf16* W1t          = (__bf16*)(ws + (6u << 20) + 131072);
    __bf16* Gt           = (__bf16*)(ws + (8u << 20));          // 76.8 MB @ 8M
    __bf16* M1t          = (__bf16*)(ws + (88u << 20));         // 76.8 MB @ 88M

    k_prep<<<dim3(128, 4), 256, 0, stream>>>(W_f, Wa1, Wa2, W1, WtF, Wa1t, Wa2t, W1t);
    k_node_fusion<<<B_, 128, 0, stream>>>(nodes, node_emb, node_prof, W_f, b_f,
                                          nodes_fusion);
    k_node_pre<<<B_, 128, 0, stream>>>(nodes_fusion, Wa1, ba1, node_pre);
    k_nf<<<dim3(N_ / 32, T_), 256, 0, stream>>>(neigh_emb, neigh_prof,
                                                WtF, b_f, Wa1t, W1t, Gt, M1t);
    k_att<<<dim3(B_, T_), 256, 0, stream>>>(neigh_idx, Gt, M1t, Wa2t, ba2,
                                            Wa3, ba3, node_pre, b1, type_agg);
    k_final<<<B_, 128, 0, stream>>>(type_agg, nodes_fusion, Wt, W2, b2, Wc, bc,
                                    out, att_out);
}

// Round 7
// 281.249 us; speedup vs baseline: 2.0965x; 1.3556x over previous
//
#include <hip/hip_runtime.h>
#include <hip/hip_bf16.h>

#define B_ 4096
#define K_ 64
#define N_ 100000
#define E_ 128
#define T_ 3

typedef __bf16 bf16x8 __attribute__((ext_vector_type(8)));
typedef float  f32x4  __attribute__((ext_vector_type(4)));

static __device__ __forceinline__ bf16x8 cvt8r(f32x4 u, f32x4 v) {
    bf16x8 o;
    o[0] = (__bf16)u[0]; o[1] = (__bf16)u[1]; o[2] = (__bf16)u[2]; o[3] = (__bf16)u[3];
    o[4] = (__bf16)v[0]; o[5] = (__bf16)v[1]; o[6] = (__bf16)v[2]; o[7] = (__bf16)v[3];
    return o;
}

typedef const __attribute__((address_space(1))) void GAS;
typedef __attribute__((address_space(3))) void LAS;
static __device__ __forceinline__ void gload16(const void* g, void* l) {
    __builtin_amdgcn_global_load_lds((GAS*)g, (LAS*)l, 16, 0, 0);
}

#define MFMA16(a, b, c) __builtin_amdgcn_mfma_f32_16x16x32_bf16((a), (b), (c), 0, 0, 0)

// ---------------------------------------------------------------------------
// Kernel 0: transpose + bf16-convert weight matrices.
// ---------------------------------------------------------------------------
__global__ __launch_bounds__(256)
void k_prep(const float* __restrict__ W_f, const float* __restrict__ Wa1,
            const float* __restrict__ Wa2, const float* __restrict__ W1,
            __bf16* __restrict__ WtF, __bf16* __restrict__ Wa1t,
            __bf16* __restrict__ Wa2t, __bf16* __restrict__ W1t) {
    const int n = blockIdx.x;
    const int k = threadIdx.x;
    if (blockIdx.y == 0) {
        WtF[n * 256 + k] = (__bf16)W_f[k * 128 + n];
    } else if (blockIdx.y == 1) {
        if (k < 128) Wa1t[n * 128 + k] = (__bf16)Wa1[k * 128 + n];
    } else if (blockIdx.y == 2) {
        if (k < 128) Wa2t[n * 128 + k] = (__bf16)Wa2[k * 128 + n];
    } else {
        if (k < 128) W1t[n * 128 + k] = (__bf16)W1[k * 128 + n];
    }
}

// ---------------------------------------------------------------------------
// Kernel 1: nodes_fusion
// ---------------------------------------------------------------------------
__global__ __launch_bounds__(128)
void k_node_fusion(const int* __restrict__ nodes,
                   const float* __restrict__ node_emb,
                   const float* __restrict__ node_prof,
                   const float* __restrict__ W_f, const float* __restrict__ b_f,
                   __bf16* __restrict__ nodes_fusion) {
    __shared__ float x[256];
    const int b = blockIdx.x;
    const int e = threadIdx.x;
    const int nd = nodes[b];
    x[e]       = node_emb[(size_t)nd * E_ + e];
    x[128 + e] = node_prof[(size_t)nd * E_ + e];
    __syncthreads();
    float acc = b_f[e];
#pragma unroll 8
    for (int i = 0; i < 256; ++i) acc = fmaf(x[i], W_f[i * E_ + e], acc);
    nodes_fusion[(size_t)b * E_ + e] = (__bf16)fmaxf(acc, 0.f);
}

// ---------------------------------------------------------------------------
// Kernel 1b: node_pre
// ---------------------------------------------------------------------------
__global__ __launch_bounds__(128)
void k_node_pre(const __bf16* __restrict__ nodes_fusion,
                const float* __restrict__ Wa1, const float* __restrict__ ba1,
                float* __restrict__ node_pre) {
    __shared__ float x[128];
    const int b = blockIdx.x;
    const int c = threadIdx.x;
    x[c] = (float)nodes_fusion[(size_t)b * E_ + c];
    __syncthreads();
    float acc = ba1[c];
#pragma unroll 8
    for (int i = 0; i < 128; ++i) acc = fmaf(x[i], Wa1[(128 + i) * E_ + c], acc);
    node_pre[(size_t)b * E_ + c] = acc;
}

// ---------------------------------------------------------------------------
// Kernel NF v3: persistent pipelined precompute.
//   512 blocks (2/CU), each grid-strides over 32-row tiles of (t, rows).
//   All weights/biases in VGPRs (no in-loop global reads except DMA+stores,
//   so counted vmcnt waits never force-drain the prefetch).
//   Per iter: wait vmcnt(4) [tile-k DMA done] -> barrier -> issue DMA(k+1)
//   -> GEMM1 -> lgkm+barrier -> GEMM2+bounce -> lgkm+barrier -> dump.
// ---------------------------------------------------------------------------
#define NF_GRID 512
#define NF_TPT (N_ / 32)          /* 3125 tiles per type */
#define NF_NJOB (NF_TPT * T_)     /* 9375 */

__global__ __launch_bounds__(256, 2)
void k_nf(const float* __restrict__ neigh_emb,
          const float* __restrict__ neigh_prof,
          const __bf16* __restrict__ WtF, const float* __restrict__ b_f,
          const __bf16* __restrict__ Wa1t, const __bf16* __restrict__ W1t,
          __bf16* __restrict__ G, __bf16* __restrict__ M1) {
    __shared__ __align__(16) float  Xf[2][32 * 256];   // 2 x 32 KB
    __shared__ __align__(16) __bf16 NFl[32 * 128];     // 8 KB

    const int tid  = threadIdx.x;
    const int wid  = tid >> 6, lane = tid & 63;
    const int lr   = lane & 15, lk = lane >> 4;

    // ---- preload weights into registers (wave owns cols wid*32..+32) ----
    bf16x8 wf[16];                 // GEMM1 [ks*2+n]
#pragma unroll
    for (int ks = 0; ks < 8; ++ks)
#pragma unroll
        for (int n = 0; n < 2; ++n)
            wf[ks * 2 + n] = *(const bf16x8*)&WtF[
                (size_t)(wid * 32 + n * 16 + lr) * 256 + ks * 32 + lk * 8];
    bf16x8 wa[8], w1r[8];          // GEMM2 [ks*2+n]
#pragma unroll
    for (int ks = 0; ks < 4; ++ks)
#pragma unroll
        for (int n = 0; n < 2; ++n) {
            wa[ks * 2 + n]  = *(const bf16x8*)&Wa1t[
                (size_t)(wid * 32 + n * 16 + lr) * 128 + ks * 32 + lk * 8];
            w1r[ks * 2 + n] = *(const bf16x8*)&W1t[
                (size_t)(wid * 32 + n * 16 + lr) * 128 + ks * 32 + lk * 8];
        }
    const float bb0 = b_f[wid * 32 + lr];
    const float bb1 = b_f[wid * 32 + 16 + lr];

    // ---- DMA stage helper: 8 rows per wave, 1 KB f32 per issue ----
    auto stage = [&](int j, int buf) {
        const int t    = j / NF_TPT;
        const int base = (j - t * NF_TPT) * 32;
        const float* embT  = neigh_emb  + (size_t)t * N_ * E_;
        const float* profT = neigh_prof + (size_t)t * N_ * E_;
#pragma unroll
        for (int i = 0; i < 8; ++i) {
            const int r  = wid * 8 + i;                // wave-uniform
            const int id = base + r;
            const int g  = lane ^ (r & 15);            // source pre-swizzle
            const float* src = (g < 32)
                ? embT  + (size_t)id * E_ + g * 4
                : profT + (size_t)id * E_ + (g - 32) * 4;
            gload16(src, (char*)&Xf[buf][0] + r * 1024);
        }
    };

    int job = blockIdx.x;
    stage(job, 0);                   // prologue: 8 DMA in flight
    int cur = 0;
    bool first = true;

    for (; job < NF_NJOB; job += NF_GRID) {
        const int tc    = job / NF_TPT;
        const int basec = (job - tc * NF_TPT) * 32;

        // tile-k DMA done (leave the 4 dump-stores of iter k-1 in flight)
        if (first) { asm volatile("s_waitcnt vmcnt(0)" ::: "memory"); first = false; }
        else       { asm volatile("s_waitcnt vmcnt(4)" ::: "memory"); }
        __builtin_amdgcn_s_barrier();
        __builtin_amdgcn_sched_barrier(0);

        // prefetch next tile into the other buffer
        const int nxt = job + NF_GRID;
        if (nxt < NF_NJOB) stage(nxt, cur ^ 1);

        const float* X = &Xf[cur][0];

        // ---- GEMM1: NF = relu(X @ W_f + b_f), K=256, rows lr & 16+lr ----
        {
            f32x4 acc1[2][2] = {};                     // [mi][n]
#pragma unroll
            for (int ks = 0; ks < 8; ++ks) {
                const int g0 = ks * 8 + lk * 2;
                const f32x4 u0 = *(const f32x4*)&X[lr * 256 + ((g0 ^ lr) << 2)];
                const f32x4 v0 = *(const f32x4*)&X[lr * 256 + (((g0 + 1) ^ lr) << 2)];
                const f32x4 u1 = *(const f32x4*)&X[(16 + lr) * 256 + ((g0 ^ lr) << 2)];
                const f32x4 v1 = *(const f32x4*)&X[(16 + lr) * 256 + (((g0 + 1) ^ lr) << 2)];
                const bf16x8 a0 = cvt8r(u0, v0);
                const bf16x8 a1 = cvt8r(u1, v1);
                acc1[0][0] = MFMA16(a0, wf[ks * 2 + 0], acc1[0][0]);
                acc1[0][1] = MFMA16(a0, wf[ks * 2 + 1], acc1[0][1]);
                acc1[1][0] = MFMA16(a1, wf[ks * 2 + 0], acc1[1][0]);
                acc1[1][1] = MFMA16(a1, wf[ks * 2 + 1], acc1[1][1]);
            }
#pragma unroll
            for (int n = 0; n < 2; ++n) {
                const int c = wid * 32 + n * 16 + lr;
                const float bb = n ? bb1 : bb0;
                const int q = c >> 3, eo = c & 7;
#pragma unroll
                for (int mi = 0; mi < 2; ++mi)
#pragma unroll
                    for (int j = 0; j < 4; ++j) {
                        const int rN = mi * 16 + lk * 4 + j;
                        NFl[rN * 128 + ((q ^ (rN & 15)) << 3) + eo] =
                            (__bf16)fmaxf(acc1[mi][n][j] + bb, 0.f);
                    }
            }
        }
        asm volatile("s_waitcnt lgkmcnt(0)" ::: "memory");
        __builtin_amdgcn_s_barrier();
        __builtin_amdgcn_sched_barrier(0);

        // ---- GEMM2a/b: G = NF @ Wa1t, M1 = NF @ W1t; bounce into Xf[cur] ----
        {
            f32x4 g2[2][2] = {}, g3[2][2] = {};
#pragma unroll
            for (int ks = 0; ks < 4; ++ks) {
                const int q = ks * 4 + lk;
                const bf16x8 a0 = *(const bf16x8*)&NFl[lr * 128 + ((q ^ lr) << 3)];
                const bf16x8 a1 = *(const bf16x8*)&NFl[(16 + lr) * 128 + ((q ^ lr) << 3)];
#pragma unroll
                for (int n = 0; n < 2; ++n) {
                    g2[0][n] = MFMA16(a0, wa[ks * 2 + n],  g2[0][n]);
                    g2[1][n] = MFMA16(a1, wa[ks * 2 + n],  g2[1][n]);
                    g3[0][n] = MFMA16(a0, w1r[ks * 2 + n], g3[0][n]);
                    g3[1][n] = MFMA16(a1, w1r[ks * 2 + n], g3[1][n]);
                }
            }
            __bf16* Gl  = (__bf16*)&Xf[cur][0];        // dead after GEMM1+barrier
            __bf16* M1l = Gl + 4096;
#pragma unroll
            for (int n = 0; n < 2; ++n) {
                const int c = wid * 32 + n * 16 + lr;
                const int q = c >> 3, eo = c & 7;
#pragma unroll
                for (int mi = 0; mi < 2; ++mi)
#pragma unroll
                    for (int j = 0; j < 4; ++j) {
                        const int rN = mi * 16 + lk * 4 + j;
                        const int sl = rN * 128 + ((q ^ (rN & 15)) << 3) + eo;
                        Gl[sl]  = (__bf16)g2[mi][n][j];
                        M1l[sl] = (__bf16)g3[mi][n][j];
                    }
            }
        }
        asm volatile("s_waitcnt lgkmcnt(0)" ::: "memory");
        __builtin_amdgcn_s_barrier();
        __builtin_amdgcn_sched_barrier(0);

        // ---- dump: 4 global_store_dwordx4 per thread (counted in vmcnt(4)) ----
        {
            const __bf16* Gl  = (const __bf16*)&Xf[cur][0];
            const __bf16* M1l = Gl + 4096;
            const int rr = tid >> 3, qq = tid & 7;
            __bf16* gout = G  + ((size_t)tc * N_ + basec + rr) * E_;
            __bf16* mout = M1 + ((size_t)tc * N_ + basec + rr) * E_;
#pragma unroll
            for (int g = 0; g < 2; ++g) {
                const int q = qq * 2 + g;
                const int p = q ^ (rr & 15);
                *(bf16x8*)(gout + q * 8) = *(const bf16x8*)&Gl[rr * 128 + (p << 3)];
                *(bf16x8*)(mout + q * 8) = *(const bf16x8*)&M1l[rr * 128 + (p << 3)];
            }
        }
        cur ^= 1;
    }
}

// ---------------------------------------------------------------------------
// Kernel ATT (unchanged from round 6)
// ---------------------------------------------------------------------------
__global__ __launch_bounds__(256, 4)
void k_att(const int* __restrict__ neigh_idx,
           const __bf16* __restrict__ G, const __bf16* __restrict__ M1,
           const __bf16* __restrict__ Wa2t,
           const float* __restrict__ ba2,
           const float* __restrict__ Wa3, const float* __restrict__ ba3,
           const float* __restrict__ node_pre,
           const float* __restrict__ b1,
           __bf16* __restrict__ type_agg) {
    __shared__ __align__(16) __bf16 Gb[64 * 128];
    __shared__ __align__(16) __bf16 Mb[64 * 128];
    __shared__ float npre[128];
    __shared__ float scp[128];
    __shared__ float att_s[64];
    __shared__ float red2[2][128];

    const int b   = blockIdx.x;
    const int t   = blockIdx.y;
    const int tid = threadIdx.x;
    const int wid = tid >> 6, lane = tid & 63;
    const int lr = lane & 15, lk = lane >> 4;

    if (tid < 128) npre[tid] = node_pre[(size_t)b * E_ + tid];

    const int* idx_row = neigh_idx + ((size_t)t * B_ + b) * K_;

#pragma unroll
    for (int i = 0; i < 4; ++i) {
        const int rowblock = wid * 16 + i * 4;
        const int row = rowblock + (lane >> 4);
        const int q = (lane & 15) ^ (row & 15);
        const int id = idx_row[row];
        const size_t goff = ((size_t)t * N_ + id) * E_ + q * 8;
        gload16(G + goff,  (char*)Gb + rowblock * 256);
        gload16(M1 + goff, (char*)Mb + rowblock * 256);
    }
    __syncthreads();

    const int mp = wid >> 1, h = wid & 1;
    const int r0 = 32 * mp + lr, r1 = r0 + 16;
    f32x4 acc[2][4] = {};
#pragma unroll
    for (int ks = 0; ks < 4; ++ks) {
        const int q = ks * 4 + lk;
        const f32x4 n0 = *(const f32x4*)&npre[q * 8];
        const f32x4 n1 = *(const f32x4*)&npre[q * 8 + 4];
        const bf16x8 g0 = *(const bf16x8*)&Gb[r0 * 128 + ((q ^ lr) << 3)];
        const bf16x8 g1 = *(const bf16x8*)&Gb[r1 * 128 + ((q ^ lr) << 3)];
        bf16x8 a0, a1;
#pragma unroll
        for (int j = 0; j < 4; ++j) {
            a0[j]     = (__bf16)fmaxf((float)g0[j]     + n0[j], 0.f);
            a0[j + 4] = (__bf16)fmaxf((float)g0[j + 4] + n1[j], 0.f);
            a1[j]     = (__bf16)fmaxf((float)g1[j]     + n0[j], 0.f);
            a1[j + 4] = (__bf16)fmaxf((float)g1[j + 4] + n1[j], 0.f);
        }
        const __bf16* wb = Wa2t + (size_t)(h * 64 + lr) * 128 + ks * 32 + lk * 8;
#pragma unroll
        for (int n = 0; n < 4; ++n) {
            const bf16x8 w = *(const bf16x8*)(wb + (size_t)n * 16 * 128);
            acc[0][n] = MFMA16(a0, w, acc[0][n]);
            acc[1][n] = MFMA16(a1, w, acc[1][n]);
        }
    }

    {
        float ba2r[4], wa3r[4];
#pragma unroll
        for (int n = 0; n < 4; ++n) {
            const int col = h * 64 + n * 16 + lr;
            ba2r[n] = ba2[col];
            wa3r[n] = Wa3[col];
        }
#pragma unroll
        for (int mi = 0; mi < 2; ++mi)
#pragma unroll
            for (int j = 0; j < 4; ++j) {
                float v = 0.f;
#pragma unroll
                for (int n = 0; n < 4; ++n)
                    v += fmaxf(acc[mi][n][j] + ba2r[n], 0.f) * wa3r[n];
                v += __shfl_xor(v, 1);
                v += __shfl_xor(v, 2);
                v += __shfl_xor(v, 4);
                v += __shfl_xor(v, 8);
                if (lr == 0)
                    scp[h * 64 + 32 * mp + mi * 16 + lk * 4 + j] = v;
            }
    }
    __syncthreads();

    if (tid < 64) {
        const float v = scp[tid] + scp[64 + tid] + ba3[0];
        float m = v;
#pragma unroll
        for (int o = 32; o > 0; o >>= 1) m = fmaxf(m, __shfl_xor(m, o));
        const float pe = __expf(v - m);
        float s = pe;
#pragma unroll
        for (int o = 32; o > 0; o >>= 1) s += __shfl_xor(s, o);
        att_s[tid] = pe / s;
    }
    __syncthreads();

    {
        const int e = tid & 127, half = tid >> 7;
        const int q = e >> 3, eo = e & 7;
        float a = 0.f;
#pragma unroll 8
        for (int n = 0; n < 32; ++n) {
            const int nn = half * 32 + n;
            a = fmaf(att_s[nn], (float)Mb[nn * 128 + ((q ^ (nn & 15)) << 3) + eo], a);
        }
        red2[half][e] = a;
    }
    __syncthreads();
    if (tid < 128) {
        const float s = red2[0][tid] + red2[1][tid];
        type_agg[((size_t)b * T_ + t) * E_ + tid] = (__bf16)fmaxf(s + b1[tid], 0.f);
    }
}

// ---------------------------------------------------------------------------
// Kernel 3: type softmax + final MLP + output head. (unchanged)
// ---------------------------------------------------------------------------
__global__ __launch_bounds__(128)
void k_final(const __bf16* __restrict__ type_agg,
             const __bf16* __restrict__ nodes_fusion,
             const float* __restrict__ Wt,
             const float* __restrict__ W2, const float* __restrict__ b2,
             const float* __restrict__ Wc, const float* __restrict__ bc,
             float* __restrict__ out, float* __restrict__ att_out) {
    __shared__ float ta[384];
    __shared__ float nfu[128];
    __shared__ float fin[128];
    __shared__ float hb[128];
    __shared__ float att[3];
    __shared__ float red[3][128];

    const int b = blockIdx.x;
    const int e = threadIdx.x;

    const float v0 = (float)type_agg[(size_t)b * 384 + e];
    const float v1 = (float)type_agg[(size_t)b * 384 + 128 + e];
    const float v2 = (float)type_agg[(size_t)b * 384 + 256 + e];
    ta[e] = v0; ta[128 + e] = v1; ta[256 + e] = v2;
    nfu[e] = (float)nodes_fusion[(size_t)b * E_ + e];

    float p0, p1, p2;
    {
        const float* w0 = Wt + (size_t)e * 3;
        const float* w1 = Wt + (size_t)(128 + e) * 3;
        const float* w2 = Wt + (size_t)(256 + e) * 3;
        p0 = v0 * w0[0] + v1 * w1[0] + v2 * w2[0];
        p1 = v0 * w0[1] + v1 * w1[1] + v2 * w2[1];
        p2 = v0 * w0[2] + v1 * w1[2] + v2 * w2[2];
    }
    red[0][e] = p0; red[1][e] = p1; red[2][e] = p2;
    __syncthreads();

    if (e < 3) {
        float s = 0.f;
        for (int i = 0; i < 128; ++i) s += red[e][i];
        red[e][0] = s;
    }
    __syncthreads();
    if (e == 0) {
        const float s0 = red[0][0], s1 = red[1][0], s2 = red[2][0];
        const float m  = fmaxf(s0, fmaxf(s1, s2));
        const float e0 = __expf(s0 - m), e1 = __expf(s1 - m), e2 = __expf(s2 - m);
        const float inv = 1.f / (e0 + e1 + e2);
        att[0] = e0 * inv; att[1] = e1 * inv; att[2] = e2 * inv;
    }
    __syncthreads();

    fin[e] = att[0] * ta[e] + att[1] * ta[128 + e] + att[2] * ta[256 + e];
    __syncthreads();

    float acc = b2[e];
#pragma unroll 8
    for (int i = 0; i < 128; ++i) acc = fmaf(fin[i], W2[i * E_ + e], acc);
    hb[e] = fmaxf(acc, 0.f);
    __syncthreads();

    float acc2 = bc[e];
#pragma unroll 8
    for (int i = 0; i < 128; ++i) acc2 = fmaf(nfu[i], Wc[i * E_ + e], acc2);
#pragma unroll 8
    for (int i = 0; i < 128; ++i) acc2 = fmaf(hb[i], Wc[(128 + i) * E_ + e], acc2);
    out[(size_t)b * E_ + e] = fmaxf(acc2, 0.f);

    if (e < 3) att_out[(size_t)b * 3 + e] = att[e];
}

// ---------------------------------------------------------------------------
extern "C" void kernel_launch(void* const* d_in, const int* in_sizes, int n_in,
                              void* d_out, int out_size, void* d_ws, size_t ws_size,
                              hipStream_t stream) {
    const int*   nodes      = (const int*)d_in[0];
    const int*   neigh_idx  = (const int*)d_in[1];
    const float* node_emb   = (const float*)d_in[2];
    const float* node_prof  = (const float*)d_in[3];
    const float* neigh_emb  = (const float*)d_in[4];
    const float* neigh_prof = (const float*)d_in[5];
    const float* W_f = (const float*)d_in[6];  const float* b_f = (const float*)d_in[7];
    const float* Wa1 = (const float*)d_in[8];  const float* ba1 = (const float*)d_in[9];
    const float* Wa2 = (const float*)d_in[10]; const float* ba2 = (const float*)d_in[11];
    const float* Wa3 = (const float*)d_in[12]; const float* ba3 = (const float*)d_in[13];
    const float* W1  = (const float*)d_in[14]; const float* b1  = (const float*)d_in[15];
    const float* W2  = (const float*)d_in[16]; const float* b2  = (const float*)d_in[17];
    const float* Wc  = (const float*)d_in[18]; const float* bc  = (const float*)d_in[19];
    const float* Wt  = (const float*)d_in[20];

    float* out     = (float*)d_out;
    float* att_out = out + (size_t)B_ * E_;

    char* ws = (char*)d_ws;
    __bf16* nodes_fusion = (__bf16*)(ws);                       // 1 MB @ 0
    float*  node_pre     = (float*)(ws + (1u << 20));           // 2 MB @ 1M
    __bf16* type_agg     = (__bf16*)(ws + (3u << 20));          // 3 MB @ 3M
    __bf16* WtF          = (__bf16*)(ws + (6u << 20));          // 64 KB
    __bf16* Wa1t         = (__bf16*)(ws + (6u << 20) + 65536);
    __bf16* Wa2t         = (__bf16*)(ws + (6u << 20) + 98304);
    __bf16* W1t          = (__bf16*)(ws + (6u << 20) + 131072);
    __bf16* Gt           = (__bf16*)(ws + (8u << 20));          // 76.8 MB @ 8M
    __bf16* M1t          = (__bf16*)(ws + (88u << 20));         // 76.8 MB @ 88M

    k_prep<<<dim3(128, 4), 256, 0, stream>>>(W_f, Wa1, Wa2, W1, WtF, Wa1t, Wa2t, W1t);
    k_node_fusion<<<B_, 128, 0, stream>>>(nodes, node_emb, node_prof, W_f, b_f,
                                          nodes_fusion);
    k_node_pre<<<B_, 128, 0, stream>>>(nodes_fusion, Wa1, ba1, node_pre);
    k_nf<<<NF_GRID, 256, 0, stream>>>(neigh_emb, neigh_prof,
                                      WtF, b_f, Wa1t, W1t, Gt, M1t);
    k_att<<<dim3(B_, T_), 256, 0, stream>>>(neigh_idx, Gt, M1t, Wa2t, ba2,
                                            Wa3, ba3, node_pre, b1, type_agg);
    k_final<<<B_, 128, 0, stream>>>(type_agg, nodes_fusion, Wt, W2, b2, Wc, bc,
                                    out, att_out);
}